// Round 4
// baseline (13265.938 us; speedup 1.0000x reference)
//
#include <hip/hip_runtime.h>
#include <hip/hip_bf16.h>

// Dims
#define E_ 256
#define H_ 256
#define B_ 64
#define S_ 512
#define T_ 12
#define START_ 10
#define STOP_ 11
#define NEG_ -10000.0f

typedef __attribute__((ext_vector_type(8))) short bf16x8;
typedef __attribute__((ext_vector_type(4))) float f32x4;

__device__ inline __hip_bfloat16 f2bf(float x) { return __float2bfloat16(x); }
__device__ inline float bf2f(__hip_bfloat16 x) { return __bfloat162float(x); }
__device__ inline unsigned short f2us(float f) {
    __hip_bfloat16 h = __float2bfloat16(f);
    unsigned short u; __builtin_memcpy(&u, &h, 2); return u;
}
__device__ inline float us2f(unsigned short u) {
    unsigned int x = ((unsigned int)u) << 16;
    float f; __builtin_memcpy(&f, &x, 4); return f;
}
__device__ inline float sigm_(float x) {
    return __builtin_amdgcn_rcpf(1.f + __builtin_amdgcn_exp2f(-1.44269504f * x));
}
__device__ inline float tanh_(float x) {
    return 2.f * __builtin_amdgcn_rcpf(1.f + __builtin_amdgcn_exp2f(-2.88539008f * x)) - 1.f;
}

// ---------------- prep: cast weights to bf16, fold biases ----------------
__global__ void k_prep(const float* wih_f, const float* whh_f,
                       const float* bih_f, const float* bhh_f,
                       const float* wih_b, const float* whh_b,
                       const float* bih_b, const float* bhh_b,
                       __hip_bfloat16* wb, __hip_bfloat16* whhb, float* bias)
{
    int i = blockIdx.x * 256 + threadIdx.x;   // 0 .. 524287
    int n = i >> 8, k = i & 255;
    float wi = (n < 1024) ? wih_f[n * 256 + k] : wih_b[(n - 1024) * 256 + k];
    float wh = (n < 1024) ? whh_f[n * 256 + k] : whh_b[(n - 1024) * 256 + k];
    wb[i] = f2bf(wi);
    whhb[i] = f2bf(wh);
    if (i < 2048)
        bias[i] = (i < 1024) ? (bih_f[i] + bhh_f[i]) : (bih_b[i - 1024] + bhh_b[i - 1024]);
}

// ---------------- gather: xb[s*64+b][e] = bf16(emb[sent[b][s]][e]) ----------------
__global__ void k_gather(const int* sent, const float* emb, __hip_bfloat16* xb)
{
    int gid = blockIdx.x * 256 + threadIdx.x;   // 32768 rows * 64 lanes
    int row = gid >> 6;                          // s*64 + b
    int l = gid & 63;
    int s = row >> 6, b = row & 63;
    int tok = sent[b * S_ + s];
    const float4 v = *reinterpret_cast<const float4*>(emb + (size_t)tok * E_ + l * 4);
    ushort4 pk;
    pk.x = f2us(v.x); pk.y = f2us(v.y); pk.z = f2us(v.z); pk.w = f2us(v.w);
    *reinterpret_cast<ushort4*>(xb + (size_t)row * E_ + l * 4) = pk;
}

// ---------------- pre-GEMM: pre[dir][s][b][j] = xb @ wb^T + bias ----------------
__global__ void k_pregemm(const __hip_bfloat16* xb, const __hip_bfloat16* wb,
                          const float* bias, __hip_bfloat16* pre)
{
    int m0 = blockIdx.x * 64;
    int n0 = blockIdx.y * 64;
    int w = threadIdx.x >> 6, l = threadIdx.x & 63;
    int lr = l & 15, lk = (l >> 4) * 8;
    const __hip_bfloat16* ap = xb + (size_t)(m0 + w * 16 + lr) * 256 + lk;
    const __hip_bfloat16* bpp = wb + (size_t)(n0 + lr) * 256 + lk;
    f32x4 acc[4] = {};
#pragma unroll
    for (int kc = 0; kc < 8; ++kc) {
        bf16x8 a = *reinterpret_cast<const bf16x8*>(ap + kc * 32);
#pragma unroll
        for (int f = 0; f < 4; ++f) {
            bf16x8 bb = *reinterpret_cast<const bf16x8*>(bpp + f * 16 * 256 + kc * 32);
            acc[f] = __builtin_amdgcn_mfma_f32_16x16x32_bf16(a, bb, acc[f], 0, 0, 0);
        }
    }
#pragma unroll
    for (int f = 0; f < 4; ++f) {
        int n = n0 + f * 16 + lr;
        float bs = bias[n];
        int dir = n >> 10, j = n & 1023;
#pragma unroll
        for (int q = 0; q < 4; ++q) {
            int m = m0 + w * 16 + (l >> 4) * 4 + q;
            pre[(size_t)dir * 33554432 + (size_t)m * 1024 + j] = f2bf(acc[f][q] + bs);
        }
    }
}

// ---------------- recurrent LSTM: tagged-word exchange, no flags, no barriers ----------------
// 32 WGs (dir x 4 batch-slice x 4 j-slice) x 4 waves. Whh register-resident (128 VGPR/lane).
// h exchange: u32 word = (bf16_h << 16) | (t+1), parity double-buffered:
//   xh[par][group=dir*4+bs][row 0..15][k 0..255]   (256 KB total, lives in MALL)
// Producer: fire-and-forget relaxed agent dword stores (dword stores are atomic -> each
// word self-verifies; no drain, no release, no flag). Consumer: poll-load the data itself,
// retry until all 64 tags == t. Mutual all-to-all dependency bounds skew to 1 step.
__launch_bounds__(256, 1)
__global__ void k_lstm_tag(const __hip_bfloat16* whhb, const __hip_bfloat16* pre,
                           const float* h0, const float* c0, __hip_bfloat16* hout,
                           unsigned int* xh)
{
    int bid = blockIdx.x;
    int dir = bid >> 4;          // 0..1
    int bs  = (bid >> 2) & 3;    // batch slice
    int jw  = bid & 3;           // j slice
    int b0 = bs * 16;
    int tid = threadIdx.x;
    int w = tid >> 6, l = tid & 63;
    int lr = l & 15, lh = l >> 4, lk = lh * 8;
    int jsub = jw * 64 + w * 16;         // this wave's 16 h-cols

    const __hip_bfloat16* wp = whhb + (size_t)dir * 262144;
    const __hip_bfloat16* prebase = pre + (size_t)dir * 33554432;
    __hip_bfloat16* hop = hout + (size_t)dir * 8388608;
    int grp = dir * 4 + bs;

    // ---- preload Whh fragments: wreg[gate][kc], col = gate*256 + jsub + lr ----
    bf16x8 wreg[4][8];
#pragma unroll
    for (int f = 0; f < 4; ++f) {
        const __hip_bfloat16* base = wp + (size_t)(f * 256 + jsub + lr) * 256 + lk;
#pragma unroll
        for (int kc = 0; kc < 8; ++kc)
            wreg[f][kc] = *reinterpret_cast<const bf16x8*>(base + kc * 32);
    }

    // ---- c state: lane holds rows lh*4+q, col jsub+lr ----
    float c[4];
#pragma unroll
    for (int q = 0; q < 4; ++q)
        c[q] = c0[(size_t)(dir * 64 + b0 + lh * 4 + q) * 256 + jsub + lr];

    for (int t = 0; t < 512; ++t) {
        int s = dir ? (511 - t) : t;

        // issue pre[t] loads early (latency hidden under the poll)
        unsigned short pr[4][4];
#pragma unroll
        for (int f = 0; f < 4; ++f)
#pragma unroll
            for (int q = 0; q < 4; ++q)
                pr[f][q] = *reinterpret_cast<const unsigned short*>(
                    prebase + (size_t)(s * 64 + b0 + lh * 4 + q) * 1024 + f * 256 + jsub + lr);

        // ---- A fragments: h_{t-1}, row lr, k = kc*32 + lh*8 + i ----
        bf16x8 areg[8];
        if (t == 0) {
            const float* hrow = h0 + (size_t)(dir * 64 + b0 + lr) * 256;
#pragma unroll
            for (int kc = 0; kc < 8; ++kc) {
                bf16x8 a;
#pragma unroll
                for (int i = 0; i < 8; ++i)
                    a[i] = (short)f2us(hrow[kc * 32 + lk + i]);
                areg[kc] = a;
            }
        } else {
            const unsigned int* xb_ =
                xh + ((((t & 1) * 8 + grp) * 16 + lr) << 8) + lh * 8;
            unsigned int v[8][8];
            unsigned int texp = (unsigned int)t;
            for (;;) {
#pragma unroll
                for (int kc = 0; kc < 8; ++kc)
#pragma unroll
                    for (int i = 0; i < 8; ++i)
                        v[kc][i] = __hip_atomic_load(xb_ + kc * 32 + i,
                                                     __ATOMIC_RELAXED,
                                                     __HIP_MEMORY_SCOPE_AGENT);
                unsigned int bad = 0;
#pragma unroll
                for (int kc = 0; kc < 8; ++kc)
#pragma unroll
                    for (int i = 0; i < 8; ++i)
                        bad |= (v[kc][i] ^ texp);
                if (!__any((bad & 0xffffu) != 0u)) break;
                __builtin_amdgcn_s_sleep(1);
            }
#pragma unroll
            for (int kc = 0; kc < 8; ++kc) {
                union { unsigned int u[4]; bf16x8 b; } A;
#pragma unroll
                for (int j = 0; j < 4; ++j)
                    A.u[j] = (v[kc][2 * j] >> 16) | (v[kc][2 * j + 1] & 0xffff0000u);
                areg[kc] = A.b;
            }
        }

        // ---- MFMA: all operands in registers ----
        f32x4 acc[4] = {};
#pragma unroll
        for (int kc = 0; kc < 8; ++kc) {
#pragma unroll
            for (int f = 0; f < 4; ++f)
                acc[f] = __builtin_amdgcn_mfma_f32_16x16x32_bf16(areg[kc], wreg[f][kc],
                                                                 acc[f], 0, 0, 0);
        }

        // ---- gates (i,f,g,o), c update, publish h ----
        unsigned int* pub = xh + (((((t + 1) & 1) * 8 + grp) * 16) << 8) + jsub + lr;
        unsigned int tag = (unsigned int)(t + 1);
#pragma unroll
        for (int q = 0; q < 4; ++q) {
            float iv = acc[0][q] + us2f(pr[0][q]);
            float fv = acc[1][q] + us2f(pr[1][q]);
            float gv = acc[2][q] + us2f(pr[2][q]);
            float ov = acc[3][q] + us2f(pr[3][q]);
            float cn = sigm_(fv) * c[q] + sigm_(iv) * tanh_(gv);
            c[q] = cn;
            float hv = sigm_(ov) * tanh_(cn);
            unsigned short hb = f2us(hv);
            __hip_atomic_store(pub + ((lh * 4 + q) << 8),
                               ((unsigned int)hb << 16) | tag,
                               __ATOMIC_RELAXED, __HIP_MEMORY_SCOPE_AGENT);
            *reinterpret_cast<unsigned short*>(
                hop + (size_t)(s * 64 + b0 + lh * 4 + q) * 256 + jsub + lr) = hb;
        }
    }
}

// ---------------- feats ----------------
__global__ void k_feats(const __hip_bfloat16* hout, const float* w_out, const float* b_out,
                        float* feats)
{
    __shared__ float wsm[12 * 512];
    __shared__ float bsm[12];
    int tid = threadIdx.x;
    for (int i = tid; i < 12 * 512; i += 256) wsm[i] = w_out[i];
    if (tid < 12) bsm[tid] = b_out[tid];
    __syncthreads();
    int w = tid >> 6, l = tid & 63;
    int row = blockIdx.x * 4 + w;
    const ushort4 uf = *reinterpret_cast<const ushort4*>(hout + (size_t)row * 256 + l * 4);
    const ushort4 ub = *reinterpret_cast<const ushort4*>(hout + 8388608 + (size_t)row * 256 + l * 4);
    float hf[4] = { us2f(uf.x), us2f(uf.y), us2f(uf.z), us2f(uf.w) };
    float hb[4] = { us2f(ub.x), us2f(ub.y), us2f(ub.z), us2f(ub.w) };
    float outv[12];
#pragma unroll
    for (int tg = 0; tg < 12; ++tg) {
        const float* wr = &wsm[tg * 512];
        float v = 0.f;
#pragma unroll
        for (int i = 0; i < 4; ++i)
            v += wr[l * 4 + i] * hf[i] + wr[256 + l * 4 + i] * hb[i];
#pragma unroll
        for (int off = 32; off >= 1; off >>= 1) v += __shfl_xor(v, off, 64);
        outv[tg] = v;
    }
    if (l == 0) {
#pragma unroll
        for (int tg = 0; tg < 12; ++tg)
            feats[(size_t)row * 12 + tg] = outv[tg] + bsm[tg];
    }
}

// ---------------- Viterbi DP + backtrace ----------------
__global__ void k_viterbi(const float* feats, const float* trans, float* out)
{
    __shared__ unsigned char bp[512][12];
    __shared__ float red[12];
    int b = blockIdx.x, l = threadIdx.x;
    bool act = l < 12;
    float trow[12];
#pragma unroll
    for (int p = 0; p < 12; ++p) trow[p] = act ? trans[l * 12 + p] : 0.f;
    float fv = (l == START_) ? 0.f : NEG_;
    for (int t = 0; t < 512; ++t) {
        float best = -3.0e38f; int bi = 0;
#pragma unroll
        for (int p = 0; p < 12; ++p) {
            float fp = __shfl(fv, p, 64) + trow[p];
            if (fp > best) { best = fp; bi = p; }   // strict > keeps FIRST max (np semantics)
        }
        float ft = act ? feats[(size_t)(t * 64 + b) * 12 + l] : 0.f;
        fv = best + ft;
        if (act) bp[t][l] = (unsigned char)bi;
    }
    float term = fv + (act ? trans[STOP_ * 12 + l] : 0.f);
    if (act) red[l] = term;
    __syncthreads();
    if (l == 0) {
        float bv = red[0]; int bestj = 0;
#pragma unroll
        for (int j = 1; j < 12; ++j)
            if (red[j] > bv) { bv = red[j]; bestj = j; }
        out[b] = bv;
        int curtag = bestj;
        for (int t = 511; t >= 0; --t) {
            out[64 + (size_t)b * 512 + t] = (float)curtag;
            curtag = bp[t][curtag];
        }
    }
}

extern "C" void kernel_launch(void* const* d_in, const int* in_sizes, int n_in,
                              void* d_out, int out_size, void* d_ws, size_t ws_size,
                              hipStream_t stream)
{
    const int*   sent  = (const int*)  d_in[0];
    const float* emb   = (const float*)d_in[1];
    const float* wih_f = (const float*)d_in[2];
    const float* whh_f = (const float*)d_in[3];
    const float* bih_f = (const float*)d_in[4];
    const float* bhh_f = (const float*)d_in[5];
    const float* wih_b = (const float*)d_in[6];
    const float* whh_b = (const float*)d_in[7];
    const float* bih_b = (const float*)d_in[8];
    const float* bhh_b = (const float*)d_in[9];
    const float* w_out = (const float*)d_in[10];
    const float* b_out = (const float*)d_in[11];
    const float* trans = (const float*)d_in[12];
    const float* h0    = (const float*)d_in[13];
    const float* c0    = (const float*)d_in[14];
    float* out = (float*)d_out;

    char* ws = (char*)d_ws;
    __hip_bfloat16* xb    = (__hip_bfloat16*)(ws);               // 16,777,216 B
    __hip_bfloat16* wb    = (__hip_bfloat16*)(ws + 16777216);    //  1,048,576 B
    __hip_bfloat16* whhb  = (__hip_bfloat16*)(ws + 17825792);    //  1,048,576 B
    float*          bias  = (float*)         (ws + 18874368);    //      8,192 B
    __hip_bfloat16* pre   = (__hip_bfloat16*)(ws + 18882560);    // 134,217,728 B
    __hip_bfloat16* hout  = (__hip_bfloat16*)(ws + 153100288);   // 33,554,432 B
    float*          feats = (float*)         (ws + 186654720);   //  1,572,864 B
    // xh ALIASES the first 256 KB of xb: xb is dead after k_pregemm, and k_lstm_tag
    // runs after it. Initial content = embedding bf16 bits, whose low-16 tag field can
    // never equal a live tag 1..512 (those are denormal patterns); 0xAA poison = 0xAAAA
    // tag, also never valid. Exact-match tags make stale data self-identifying.
    unsigned int*   xhx   = (unsigned int*)(ws);                 //    262,144 B (alias)
    // total 188,227,584 B

    hipLaunchKernelGGL(k_prep, dim3(2048), dim3(256), 0, stream,
                       wih_f, whh_f, bih_f, bhh_f, wih_b, whh_b, bih_b, bhh_b,
                       wb, whhb, bias);
    hipLaunchKernelGGL(k_gather, dim3(8192), dim3(256), 0, stream, sent, emb, xb);
    hipLaunchKernelGGL(k_pregemm, dim3(512, 32), dim3(256), 0, stream, xb, wb, bias, pre);
    hipLaunchKernelGGL(k_lstm_tag, dim3(32), dim3(256), 0, stream,
                       whhb, pre, h0, c0, hout, xhx);
    hipLaunchKernelGGL(k_feats, dim3(8192), dim3(256), 0, stream, hout, w_out, b_out, feats);
    hipLaunchKernelGGL(k_viterbi, dim3(64), dim3(64), 0, stream, feats, trans, out);
}

// Round 5
// 4326.862 us; speedup vs baseline: 3.0659x; 3.0659x over previous
//
#include <hip/hip_runtime.h>
#include <hip/hip_bf16.h>

// Dims
#define E_ 256
#define H_ 256
#define B_ 64
#define S_ 512
#define T_ 12
#define START_ 10
#define STOP_ 11
#define NEG_ -10000.0f

typedef __attribute__((ext_vector_type(8))) short bf16x8;
typedef __attribute__((ext_vector_type(4))) float f32x4;

__device__ inline __hip_bfloat16 f2bf(float x) { return __float2bfloat16(x); }
__device__ inline float bf2f(__hip_bfloat16 x) { return __bfloat162float(x); }
__device__ inline unsigned short f2us(float f) {
    __hip_bfloat16 h = __float2bfloat16(f);
    unsigned short u; __builtin_memcpy(&u, &h, 2); return u;
}
__device__ inline float us2f(unsigned short u) {
    unsigned int x = ((unsigned int)u) << 16;
    float f; __builtin_memcpy(&f, &x, 4); return f;
}
__device__ inline float sigm_(float x) {
    return __builtin_amdgcn_rcpf(1.f + __builtin_amdgcn_exp2f(-1.44269504f * x));
}
__device__ inline float tanh_(float x) {
    return 2.f * __builtin_amdgcn_rcpf(1.f + __builtin_amdgcn_exp2f(-2.88539008f * x)) - 1.f;
}

// ---------------- prep: cast weights to bf16, fold biases ----------------
__global__ void k_prep(const float* wih_f, const float* whh_f,
                       const float* bih_f, const float* bhh_f,
                       const float* wih_b, const float* whh_b,
                       const float* bih_b, const float* bhh_b,
                       __hip_bfloat16* wb, __hip_bfloat16* whhb, float* bias)
{
    int i = blockIdx.x * 256 + threadIdx.x;   // 0 .. 524287
    int n = i >> 8, k = i & 255;
    float wi = (n < 1024) ? wih_f[n * 256 + k] : wih_b[(n - 1024) * 256 + k];
    float wh = (n < 1024) ? whh_f[n * 256 + k] : whh_b[(n - 1024) * 256 + k];
    wb[i] = f2bf(wi);
    whhb[i] = f2bf(wh);
    if (i < 2048)
        bias[i] = (i < 1024) ? (bih_f[i] + bhh_f[i]) : (bih_b[i - 1024] + bhh_b[i - 1024]);
}

// ---------------- gather: xb[s*64+b][e] = bf16(emb[sent[b][s]][e]) ----------------
__global__ void k_gather(const int* sent, const float* emb, __hip_bfloat16* xb)
{
    int gid = blockIdx.x * 256 + threadIdx.x;   // 32768 rows * 64 lanes
    int row = gid >> 6;                          // s*64 + b
    int l = gid & 63;
    int s = row >> 6, b = row & 63;
    int tok = sent[b * S_ + s];
    const float4 v = *reinterpret_cast<const float4*>(emb + (size_t)tok * E_ + l * 4);
    ushort4 pk;
    pk.x = f2us(v.x); pk.y = f2us(v.y); pk.z = f2us(v.z); pk.w = f2us(v.w);
    *reinterpret_cast<ushort4*>(xb + (size_t)row * E_ + l * 4) = pk;
}

// ---------------- pre-GEMM: pre[dir][s][b][j] = xb @ wb^T + bias ----------------
__global__ void k_pregemm(const __hip_bfloat16* xb, const __hip_bfloat16* wb,
                          const float* bias, __hip_bfloat16* pre)
{
    int m0 = blockIdx.x * 64;
    int n0 = blockIdx.y * 64;
    int w = threadIdx.x >> 6, l = threadIdx.x & 63;
    int lr = l & 15, lk = (l >> 4) * 8;
    const __hip_bfloat16* ap = xb + (size_t)(m0 + w * 16 + lr) * 256 + lk;
    const __hip_bfloat16* bpp = wb + (size_t)(n0 + lr) * 256 + lk;
    f32x4 acc[4] = {};
#pragma unroll
    for (int kc = 0; kc < 8; ++kc) {
        bf16x8 a = *reinterpret_cast<const bf16x8*>(ap + kc * 32);
#pragma unroll
        for (int f = 0; f < 4; ++f) {
            bf16x8 bb = *reinterpret_cast<const bf16x8*>(bpp + f * 16 * 256 + kc * 32);
            acc[f] = __builtin_amdgcn_mfma_f32_16x16x32_bf16(a, bb, acc[f], 0, 0, 0);
        }
    }
#pragma unroll
    for (int f = 0; f < 4; ++f) {
        int n = n0 + f * 16 + lr;
        float bs = bias[n];
        int dir = n >> 10, j = n & 1023;
#pragma unroll
        for (int q = 0; q < 4; ++q) {
            int m = m0 + w * 16 + (l >> 4) * 4 + q;
            pre[(size_t)dir * 33554432 + (size_t)m * 1024 + j] = f2bf(acc[f][q] + bs);
        }
    }
}

// ---------------- recurrent LSTM: 8 WGs x 1024 threads, NO cross-WG comm ----------------
// WG = (dir, batch-slice of 16). 16 waves; wave w owns j-cols [w*16, w*16+16) x 4 gates.
// Full Whh(dir) = 512 KB register-resident across the WG (128 VGPR/lane).
// Per step: h exchanged via LDS double buffer + one __syncthreads (intra-CU only).
__launch_bounds__(1024, 4)
__global__ void k_lstm(const __hip_bfloat16* whhb, const __hip_bfloat16* pre,
                       const float* h0, const float* c0, __hip_bfloat16* hout)
{
    __shared__ __hip_bfloat16 hbuf[2][16][264];   // row stride 528B -> 2-way (free) on b128
    int bid = blockIdx.x;
    int dir = bid >> 2;          // 0..1
    int bs  = bid & 3;           // batch slice
    int b0 = bs * 16;
    int tid = threadIdx.x;
    int w = tid >> 6, l = tid & 63;
    int lr = l & 15, lh = l >> 4, lk = lh * 8;
    int jsub = w * 16;           // this wave's 16 h-cols (j), gates at n = f*256 + jsub + lr

    const __hip_bfloat16* wp = whhb + (size_t)dir * 262144;
    const __hip_bfloat16* prebase = pre + (size_t)dir * 33554432;
    __hip_bfloat16* hop = hout + (size_t)dir * 8388608;

    // ---- preload full Whh slice: wreg[gate][kc] (128 VGPR/lane) ----
    bf16x8 wreg[4][8];
#pragma unroll
    for (int f = 0; f < 4; ++f) {
        const __hip_bfloat16* base = wp + (size_t)(f * 256 + jsub + lr) * 256 + lk;
#pragma unroll
        for (int kc = 0; kc < 8; ++kc)
            wreg[f][kc] = *reinterpret_cast<const bf16x8*>(base + kc * 32);
    }

    // ---- init h -> hbuf[0] (1024 threads x 4 values) ----
    {
        int idx = tid * 4;
        int row = idx >> 8, k = idx & 255;
        const float* src = h0 + (size_t)(dir * 64 + b0 + row) * 256 + k;
        ushort4 pk;
        pk.x = f2us(src[0]); pk.y = f2us(src[1]); pk.z = f2us(src[2]); pk.w = f2us(src[3]);
        *reinterpret_cast<ushort4*>(&hbuf[0][row][k]) = pk;
    }

    // ---- c state: lane owns rows lh*4+q, col jsub+lr ----
    float c[4];
#pragma unroll
    for (int q = 0; q < 4; ++q)
        c[q] = c0[(size_t)(dir * 64 + b0 + lh * 4 + q) * 256 + jsub + lr];
    __syncthreads();

    for (int t = 0; t < 512; ++t) {
        int s = dir ? (511 - t) : t;
        int cur = t & 1, nxt = cur ^ 1;

        // issue pre[t] loads early (consumed after MFMA -> latency hidden)
        unsigned short pr[4][4];
#pragma unroll
        for (int f = 0; f < 4; ++f)
#pragma unroll
            for (int q = 0; q < 4; ++q)
                pr[f][q] = *reinterpret_cast<const unsigned short*>(
                    prebase + (size_t)(s * 64 + b0 + lh * 4 + q) * 1024 + f * 256 + jsub + lr);

        // ---- A fragments from LDS: row lr, k = kc*32 + lh*8 ----
        bf16x8 areg[8];
#pragma unroll
        for (int kc = 0; kc < 8; ++kc)
            areg[kc] = *reinterpret_cast<const bf16x8*>(&hbuf[cur][lr][kc * 32 + lk]);

        // ---- MFMA: all operands in registers ----
        f32x4 acc[4] = {};
#pragma unroll
        for (int kc = 0; kc < 8; ++kc) {
#pragma unroll
            for (int f = 0; f < 4; ++f)
                acc[f] = __builtin_amdgcn_mfma_f32_16x16x32_bf16(areg[kc], wreg[f][kc],
                                                                 acc[f], 0, 0, 0);
        }

        // ---- gates (i,f,g,o), c update, h -> LDS + global ----
#pragma unroll
        for (int q = 0; q < 4; ++q) {
            float iv = acc[0][q] + us2f(pr[0][q]);
            float fv = acc[1][q] + us2f(pr[1][q]);
            float gv = acc[2][q] + us2f(pr[2][q]);
            float ov = acc[3][q] + us2f(pr[3][q]);
            float cn = sigm_(fv) * c[q] + sigm_(iv) * tanh_(gv);
            c[q] = cn;
            float hv = sigm_(ov) * tanh_(cn);
            unsigned short hb = f2us(hv);
            int row = lh * 4 + q;
            *reinterpret_cast<unsigned short*>(&hbuf[nxt][row][jsub + lr]) = hb;
            *reinterpret_cast<unsigned short*>(
                hop + (size_t)(s * 64 + b0 + row) * 256 + jsub + lr) = hb;
        }
        __syncthreads();
    }
}

// ---------------- feats ----------------
__global__ void k_feats(const __hip_bfloat16* hout, const float* w_out, const float* b_out,
                        float* feats)
{
    __shared__ float wsm[12 * 512];
    __shared__ float bsm[12];
    int tid = threadIdx.x;
    for (int i = tid; i < 12 * 512; i += 256) wsm[i] = w_out[i];
    if (tid < 12) bsm[tid] = b_out[tid];
    __syncthreads();
    int w = tid >> 6, l = tid & 63;
    int row = blockIdx.x * 4 + w;
    const ushort4 uf = *reinterpret_cast<const ushort4*>(hout + (size_t)row * 256 + l * 4);
    const ushort4 ub = *reinterpret_cast<const ushort4*>(hout + 8388608 + (size_t)row * 256 + l * 4);
    float hf[4] = { us2f(uf.x), us2f(uf.y), us2f(uf.z), us2f(uf.w) };
    float hb[4] = { us2f(ub.x), us2f(ub.y), us2f(ub.z), us2f(ub.w) };
    float outv[12];
#pragma unroll
    for (int tg = 0; tg < 12; ++tg) {
        const float* wr = &wsm[tg * 512];
        float v = 0.f;
#pragma unroll
        for (int i = 0; i < 4; ++i)
            v += wr[l * 4 + i] * hf[i] + wr[256 + l * 4 + i] * hb[i];
#pragma unroll
        for (int off = 32; off >= 1; off >>= 1) v += __shfl_xor(v, off, 64);
        outv[tg] = v;
    }
    if (l == 0) {
#pragma unroll
        for (int tg = 0; tg < 12; ++tg)
            feats[(size_t)row * 12 + tg] = outv[tg] + bsm[tg];
    }
}

// ---------------- Viterbi DP + backtrace ----------------
__global__ void k_viterbi(const float* feats, const float* trans, float* out)
{
    __shared__ unsigned char bp[512][12];
    __shared__ float red[12];
    int b = blockIdx.x, l = threadIdx.x;
    bool act = l < 12;
    float trow[12];
#pragma unroll
    for (int p = 0; p < 12; ++p) trow[p] = act ? trans[l * 12 + p] : 0.f;
    float fv = (l == START_) ? 0.f : NEG_;
    for (int t = 0; t < 512; ++t) {
        float best = -3.0e38f; int bi = 0;
#pragma unroll
        for (int p = 0; p < 12; ++p) {
            float fp = __shfl(fv, p, 64) + trow[p];
            if (fp > best) { best = fp; bi = p; }   // strict > keeps FIRST max (np semantics)
        }
        float ft = act ? feats[(size_t)(t * 64 + b) * 12 + l] : 0.f;
        fv = best + ft;
        if (act) bp[t][l] = (unsigned char)bi;
    }
    float term = fv + (act ? trans[STOP_ * 12 + l] : 0.f);
    if (act) red[l] = term;
    __syncthreads();
    if (l == 0) {
        float bv = red[0]; int bestj = 0;
#pragma unroll
        for (int j = 1; j < 12; ++j)
            if (red[j] > bv) { bv = red[j]; bestj = j; }
        out[b] = bv;
        int curtag = bestj;
        for (int t = 511; t >= 0; --t) {
            out[64 + (size_t)b * 512 + t] = (float)curtag;
            curtag = bp[t][curtag];
        }
    }
}

extern "C" void kernel_launch(void* const* d_in, const int* in_sizes, int n_in,
                              void* d_out, int out_size, void* d_ws, size_t ws_size,
                              hipStream_t stream)
{
    const int*   sent  = (const int*)  d_in[0];
    const float* emb   = (const float*)d_in[1];
    const float* wih_f = (const float*)d_in[2];
    const float* whh_f = (const float*)d_in[3];
    const float* bih_f = (const float*)d_in[4];
    const float* bhh_f = (const float*)d_in[5];
    const float* wih_b = (const float*)d_in[6];
    const float* whh_b = (const float*)d_in[7];
    const float* bih_b = (const float*)d_in[8];
    const float* bhh_b = (const float*)d_in[9];
    const float* w_out = (const float*)d_in[10];
    const float* b_out = (const float*)d_in[11];
    const float* trans = (const float*)d_in[12];
    const float* h0    = (const float*)d_in[13];
    const float* c0    = (const float*)d_in[14];
    float* out = (float*)d_out;

    char* ws = (char*)d_ws;
    __hip_bfloat16* xb    = (__hip_bfloat16*)(ws);               // 16,777,216 B
    __hip_bfloat16* wb    = (__hip_bfloat16*)(ws + 16777216);    //  1,048,576 B
    __hip_bfloat16* whhb  = (__hip_bfloat16*)(ws + 17825792);    //  1,048,576 B
    float*          bias  = (float*)         (ws + 18874368);    //      8,192 B
    __hip_bfloat16* pre   = (__hip_bfloat16*)(ws + 18882560);    // 134,217,728 B
    __hip_bfloat16* hout  = (__hip_bfloat16*)(ws + 153100288);   // 33,554,432 B
    float*          feats = (float*)         (ws + 186654720);   //  1,572,864 B
    // total 188,227,584 B

    hipLaunchKernelGGL(k_prep, dim3(2048), dim3(256), 0, stream,
                       wih_f, whh_f, bih_f, bhh_f, wih_b, whh_b, bih_b, bhh_b,
                       wb, whhb, bias);
    hipLaunchKernelGGL(k_gather, dim3(8192), dim3(256), 0, stream, sent, emb, xb);
    hipLaunchKernelGGL(k_pregemm, dim3(512, 32), dim3(256), 0, stream, xb, wb, bias, pre);
    hipLaunchKernelGGL(k_lstm, dim3(8), dim3(1024), 0, stream, whhb, pre, h0, c0, hout);
    hipLaunchKernelGGL(k_feats, dim3(8192), dim3(256), 0, stream, hout, w_out, b_out, feats);
    hipLaunchKernelGGL(k_viterbi, dim3(64), dim3(64), 0, stream, feats, trans, out);
}

// Round 6
// 1772.718 us; speedup vs baseline: 7.4834x; 2.4408x over previous
//
#include <hip/hip_runtime.h>
#include <hip/hip_bf16.h>

// Dims
#define E_ 256
#define H_ 256
#define B_ 64
#define S_ 512
#define T_ 12
#define START_ 10
#define STOP_ 11
#define NEG_ -10000.0f

typedef __attribute__((ext_vector_type(8))) short bf16x8;
typedef __attribute__((ext_vector_type(4))) float f32x4;
typedef __attribute__((ext_vector_type(4))) int i32x4;

__device__ inline __hip_bfloat16 f2bf(float x) { return __float2bfloat16(x); }
__device__ inline unsigned short f2us(float f) {
    __hip_bfloat16 h = __float2bfloat16(f);
    unsigned short u; __builtin_memcpy(&u, &h, 2); return u;
}
__device__ inline float us2f(unsigned short u) {
    unsigned int x = ((unsigned int)u) << 16;
    float f; __builtin_memcpy(&f, &x, 4); return f;
}
__device__ inline float sigm_(float x) {
    return __builtin_amdgcn_rcpf(1.f + __builtin_amdgcn_exp2f(-1.44269504f * x));
}
__device__ inline float tanh_(float x) {
    return 2.f * __builtin_amdgcn_rcpf(1.f + __builtin_amdgcn_exp2f(-2.88539008f * x)) - 1.f;
}

// ---------------- prep: cast Wih to bf16, fold biases, zero h0max slot ----------------
__global__ void k_prep(const float* wih_f, const float* bih_f, const float* bhh_f,
                       const float* wih_b, const float* bih_b, const float* bhh_b,
                       __hip_bfloat16* wb, float* bias, int* h0maxi)
{
    int i = blockIdx.x * 256 + threadIdx.x;   // 0 .. 524287
    int n = i >> 8, k = i & 255;
    float wi = (n < 1024) ? wih_f[n * 256 + k] : wih_b[(n - 1024) * 256 + k];
    wb[i] = f2bf(wi);
    if (i < 2048)
        bias[i] = (i < 1024) ? (bih_f[i] + bhh_f[i]) : (bih_b[i - 1024] + bhh_b[i - 1024]);
    if (i == 0) *h0maxi = 0;
}

// ---------------- quantize Whh rows to i8 with per-row scale ----------------
// wq[n][k], n = dir*1024 + gate*256 + j;  wscale[n] = max|row|/127
__global__ void k_wq(const float* whh_f, const float* whh_b,
                     signed char* wq, float* wscale)
{
    int wv = threadIdx.x >> 6, l = threadIdx.x & 63;
    int n = blockIdx.x * 4 + wv;             // 0..2047
    const float* src = (n < 1024) ? (whh_f + (size_t)n * 256)
                                  : (whh_b + (size_t)(n - 1024) * 256);
    float4 v = *reinterpret_cast<const float4*>(src + l * 4);
    float amax = fmaxf(fmaxf(fabsf(v.x), fabsf(v.y)), fmaxf(fabsf(v.z), fabsf(v.w)));
#pragma unroll
    for (int off = 32; off >= 1; off >>= 1) amax = fmaxf(amax, __shfl_xor(amax, off, 64));
    amax = fmaxf(amax, 1e-20f);
    float inv = 127.f / amax;
    int q0 = (int)rintf(v.x * inv), q1 = (int)rintf(v.y * inv);
    int q2 = (int)rintf(v.z * inv), q3 = (int)rintf(v.w * inv);
    unsigned int pk = (q0 & 255) | ((q1 & 255) << 8) | ((q2 & 255) << 16) | ((q3 & 255) << 24);
    *reinterpret_cast<unsigned int*>(wq + (size_t)n * 256 + l * 4) = pk;
    if (l == 0) wscale[n] = amax * (1.f / 127.f);
}

// ---------------- h0 abs-max (positive-float int atomicMax) ----------------
__global__ void k_h0max(const float* h0, int* h0maxi)
{
    int i = blockIdx.x * 256 + threadIdx.x;   // 32768
    float v = fabsf(h0[i]);
#pragma unroll
    for (int off = 32; off >= 1; off >>= 1) v = fmaxf(v, __shfl_xor(v, off, 64));
    if ((threadIdx.x & 63) == 0) atomicMax(h0maxi, __float_as_int(v));
}

// ---------------- quantize h0 with the global scale ----------------
__global__ void k_h0q(const float* h0, const int* h0maxi, signed char* h0q)
{
    int i = blockIdx.x * 1024 + threadIdx.x;  // 32768
    float s0 = fmaxf(__int_as_float(*h0maxi), 1e-20f);
    h0q[i] = (signed char)(int)rintf(h0[i] * (127.f / s0));
}

// ---------------- gather: xb[s*64+b][e] = bf16(emb[sent[b][s]][e]) ----------------
__global__ void k_gather(const int* sent, const float* emb, __hip_bfloat16* xb)
{
    int gid = blockIdx.x * 256 + threadIdx.x;   // 32768 rows * 64 lanes
    int row = gid >> 6;
    int l = gid & 63;
    int s = row >> 6, b = row & 63;
    int tok = sent[b * S_ + s];
    const float4 v = *reinterpret_cast<const float4*>(emb + (size_t)tok * E_ + l * 4);
    ushort4 pk;
    pk.x = f2us(v.x); pk.y = f2us(v.y); pk.z = f2us(v.z); pk.w = f2us(v.w);
    *reinterpret_cast<ushort4*>(xb + (size_t)row * E_ + l * 4) = pk;
}

// ---------------- pre-GEMM: pre[dir][s][b][j] = xb @ wb^T + bias ----------------
__global__ void k_pregemm(const __hip_bfloat16* xb, const __hip_bfloat16* wb,
                          const float* bias, __hip_bfloat16* pre)
{
    int m0 = blockIdx.x * 64;
    int n0 = blockIdx.y * 64;
    int w = threadIdx.x >> 6, l = threadIdx.x & 63;
    int lr = l & 15, lk = (l >> 4) * 8;
    const __hip_bfloat16* ap = xb + (size_t)(m0 + w * 16 + lr) * 256 + lk;
    const __hip_bfloat16* bpp = wb + (size_t)(n0 + lr) * 256 + lk;
    f32x4 acc[4] = {};
#pragma unroll
    for (int kc = 0; kc < 8; ++kc) {
        bf16x8 a = *reinterpret_cast<const bf16x8*>(ap + kc * 32);
#pragma unroll
        for (int f = 0; f < 4; ++f) {
            bf16x8 bb = *reinterpret_cast<const bf16x8*>(bpp + f * 16 * 256 + kc * 32);
            acc[f] = __builtin_amdgcn_mfma_f32_16x16x32_bf16(a, bb, acc[f], 0, 0, 0);
        }
    }
#pragma unroll
    for (int f = 0; f < 4; ++f) {
        int n = n0 + f * 16 + lr;
        float bs = bias[n];
        int dir = n >> 10, j = n & 1023;
#pragma unroll
        for (int q = 0; q < 4; ++q) {
            int m = m0 + w * 16 + (l >> 4) * 4 + q;
            pre[(size_t)dir * 33554432 + (size_t)m * 1024 + j] = f2bf(acc[f][q] + bs);
        }
    }
}

// ---------------- recurrent LSTM: i8 MFMA, full Whh(dir) register-resident ----------------
// 8 WGs = (dir x 4 batch-slices of 16), 1024 threads = 16 waves (4/SIMD, 128-VGPR cap).
// Weights: mfma_i32_16x16x64_i8 -> K=64 per 4 VGPR -> 64 VGPR/lane for the whole slice.
// g = (i32 acc) * (s_h * s_n) + pre;  s_n per gate-row, s_h = 1/127 (h in (-1,1)),
// s_h(t=0) = max|h0|/127. h exchanged via i8 LDS double buffer + one barrier per step.
__launch_bounds__(1024, 4)
__global__ void k_lstm_i8(const signed char* wq, const float* wsc,
                          const __hip_bfloat16* pre, const signed char* h0q,
                          const int* h0maxi, const float* c0,
                          __hip_bfloat16* hout)
{
    __shared__ signed char hq[2][16][272];   // stride 272B: 16B-aligned, bank-spread
    int bid = blockIdx.x;
    int dir = bid >> 2, bs = bid & 3, b0 = bs * 16;
    int tid = threadIdx.x;
    int w = tid >> 6, l = tid & 63;
    int lr = l & 15, lh = l >> 4;
    int jsub = w * 16;                        // this wave's 16 h-cols

    const signed char* wqp = wq + (size_t)dir * 262144;
    const float* wscp = wsc + dir * 1024;
    const __hip_bfloat16* prebase = pre + (size_t)dir * 33554432;
    __hip_bfloat16* hop = hout + (size_t)dir * 8388608;

    // ---- preload Whh i8 fragments: wreg[gate][kc] (64 VGPR), scales sn[gate] ----
    i32x4 wreg[4][4];
    float sn[4];
#pragma unroll
    for (int f = 0; f < 4; ++f) {
        const signed char* base = wqp + (size_t)(f * 256 + jsub + lr) * 256 + lh * 16;
#pragma unroll
        for (int kc = 0; kc < 4; ++kc)
            wreg[f][kc] = *reinterpret_cast<const i32x4*>(base + kc * 64);
        sn[f] = wscp[f * 256 + jsub + lr];
    }

    // ---- c state: lane owns rows lh*4+q, col jsub+lr ----
    float c[4];
#pragma unroll
    for (int q = 0; q < 4; ++q)
        c[q] = c0[(size_t)(dir * 64 + b0 + lh * 4 + q) * 256 + jsub + lr];

    // ---- init hq[0] from quantized h0 ----
    {
        int idx = tid * 4;
        int row = idx >> 8, k = idx & 255;
        *reinterpret_cast<int*>(&hq[0][row][k]) =
            *reinterpret_cast<const int*>(h0q + (size_t)(dir * 64 + b0 + row) * 256 + k);
    }
    __syncthreads();

    float shs = fmaxf(__int_as_float(*h0maxi), 1e-20f) * (1.f / 127.f);  // t=0 h scale

    for (int t = 0; t < 512; ++t) {
        int s = dir ? (511 - t) : t;
        int cur = t & 1, nxt = cur ^ 1;

        // prefetch pre[t] (consumed at epilogue; latency hidden under LDS+MFMA)
        unsigned short pr[4][4];
#pragma unroll
        for (int f = 0; f < 4; ++f)
#pragma unroll
            for (int q = 0; q < 4; ++q)
                pr[f][q] = *reinterpret_cast<const unsigned short*>(
                    prebase + (size_t)(s * 64 + b0 + lh * 4 + q) * 1024 + f * 256 + jsub + lr);

        // ---- MFMA over K=256 in 4 chunks of 64 ----
        i32x4 acc[4] = {};
#pragma unroll
        for (int kc = 0; kc < 4; ++kc) {
            i32x4 a = *reinterpret_cast<const i32x4*>(&hq[cur][lr][kc * 64 + lh * 16]);
#pragma unroll
            for (int f = 0; f < 4; ++f)
                acc[f] = __builtin_amdgcn_mfma_i32_16x16x64_i8(a, wreg[f][kc], acc[f], 0, 0, 0);
        }

        // ---- gates (i,f,g,o), c update, h -> LDS(i8) + global(bf16) ----
        float sf0 = shs * sn[0], sf1 = shs * sn[1], sf2 = shs * sn[2], sf3 = shs * sn[3];
#pragma unroll
        for (int q = 0; q < 4; ++q) {
            float iv = (float)acc[0][q] * sf0 + us2f(pr[0][q]);
            float fv = (float)acc[1][q] * sf1 + us2f(pr[1][q]);
            float gv = (float)acc[2][q] * sf2 + us2f(pr[2][q]);
            float ov = (float)acc[3][q] * sf3 + us2f(pr[3][q]);
            float cn = sigm_(fv) * c[q] + sigm_(iv) * tanh_(gv);
            c[q] = cn;
            float hv = sigm_(ov) * tanh_(cn);
            int row = lh * 4 + q;
            hq[nxt][row][jsub + lr] = (signed char)(int)rintf(hv * 127.f);
            *reinterpret_cast<unsigned short*>(
                hop + (size_t)(s * 64 + b0 + row) * 256 + jsub + lr) = f2us(hv);
        }
        shs = 1.f / 127.f;
        __syncthreads();
    }
}

// ---------------- feats ----------------
__global__ void k_feats(const __hip_bfloat16* hout, const float* w_out, const float* b_out,
                        float* feats)
{
    __shared__ float wsm[12 * 512];
    __shared__ float bsm[12];
    int tid = threadIdx.x;
    for (int i = tid; i < 12 * 512; i += 256) wsm[i] = w_out[i];
    if (tid < 12) bsm[tid] = b_out[tid];
    __syncthreads();
    int w = tid >> 6, l = tid & 63;
    int row = blockIdx.x * 4 + w;
    const ushort4 uf = *reinterpret_cast<const ushort4*>(hout + (size_t)row * 256 + l * 4);
    const ushort4 ub = *reinterpret_cast<const ushort4*>(hout + 8388608 + (size_t)row * 256 + l * 4);
    float hf[4] = { us2f(uf.x), us2f(uf.y), us2f(uf.z), us2f(uf.w) };
    float hb[4] = { us2f(ub.x), us2f(ub.y), us2f(ub.z), us2f(ub.w) };
    float outv[12];
#pragma unroll
    for (int tg = 0; tg < 12; ++tg) {
        const float* wr = &wsm[tg * 512];
        float v = 0.f;
#pragma unroll
        for (int i = 0; i < 4; ++i)
            v += wr[l * 4 + i] * hf[i] + wr[256 + l * 4 + i] * hb[i];
#pragma unroll
        for (int off = 32; off >= 1; off >>= 1) v += __shfl_xor(v, off, 64);
        outv[tg] = v;
    }
    if (l == 0) {
#pragma unroll
        for (int tg = 0; tg < 12; ++tg)
            feats[(size_t)row * 12 + tg] = outv[tg] + bsm[tg];
    }
}

// ---------------- Viterbi DP + backtrace ----------------
__global__ void k_viterbi(const float* feats, const float* trans, float* out)
{
    __shared__ unsigned char bp[512][12];
    __shared__ float red[12];
    int b = blockIdx.x, l = threadIdx.x;
    bool act = l < 12;
    float trow[12];
#pragma unroll
    for (int p = 0; p < 12; ++p) trow[p] = act ? trans[l * 12 + p] : 0.f;
    float fv = (l == START_) ? 0.f : NEG_;
    for (int t = 0; t < 512; ++t) {
        float best = -3.0e38f; int bi = 0;
#pragma unroll
        for (int p = 0; p < 12; ++p) {
            float fp = __shfl(fv, p, 64) + trow[p];
            if (fp > best) { best = fp; bi = p; }   // strict > keeps FIRST max (np semantics)
        }
        float ft = act ? feats[(size_t)(t * 64 + b) * 12 + l] : 0.f;
        fv = best + ft;
        if (act) bp[t][l] = (unsigned char)bi;
    }
    float term = fv + (act ? trans[STOP_ * 12 + l] : 0.f);
    if (act) red[l] = term;
    __syncthreads();
    if (l == 0) {
        float bv = red[0]; int bestj = 0;
#pragma unroll
        for (int j = 1; j < 12; ++j)
            if (red[j] > bv) { bv = red[j]; bestj = j; }
        out[b] = bv;
        int curtag = bestj;
        for (int t = 511; t >= 0; --t) {
            out[64 + (size_t)b * 512 + t] = (float)curtag;
            curtag = bp[t][curtag];
        }
    }
}

extern "C" void kernel_launch(void* const* d_in, const int* in_sizes, int n_in,
                              void* d_out, int out_size, void* d_ws, size_t ws_size,
                              hipStream_t stream)
{
    const int*   sent  = (const int*)  d_in[0];
    const float* emb   = (const float*)d_in[1];
    const float* wih_f = (const float*)d_in[2];
    const float* whh_f = (const float*)d_in[3];
    const float* bih_f = (const float*)d_in[4];
    const float* bhh_f = (const float*)d_in[5];
    const float* wih_b = (const float*)d_in[6];
    const float* whh_b = (const float*)d_in[7];
    const float* bih_b = (const float*)d_in[8];
    const float* bhh_b = (const float*)d_in[9];
    const float* w_out = (const float*)d_in[10];
    const float* b_out = (const float*)d_in[11];
    const float* trans = (const float*)d_in[12];
    const float* h0    = (const float*)d_in[13];
    const float* c0    = (const float*)d_in[14];
    float* out = (float*)d_out;

    char* ws = (char*)d_ws;
    __hip_bfloat16* xb    = (__hip_bfloat16*)(ws);               //  16,777,216 B
    __hip_bfloat16* wb    = (__hip_bfloat16*)(ws + 16777216);    //   1,048,576 B
    signed char*    wq    = (signed char*)   (ws + 17825792);    //     524,288 B
    float*          wsc   = (float*)         (ws + 18350080);    //       8,192 B
    signed char*    h0q   = (signed char*)   (ws + 18358272);    //      32,768 B
    int*            h0mx  = (int*)           (ws + 18391040);    //         128 B
    float*          bias  = (float*)         (ws + 18391168);    //       8,192 B
    __hip_bfloat16* pre   = (__hip_bfloat16*)(ws + 18399360);    // 134,217,728 B
    __hip_bfloat16* hout  = (__hip_bfloat16*)(ws + 152617088);   //  33,554,432 B
    float*          feats = (float*)         (ws + 186171520);   //   1,572,864 B
    // total 187,744,384 B

    hipLaunchKernelGGL(k_prep, dim3(2048), dim3(256), 0, stream,
                       wih_f, bih_f, bhh_f, wih_b, bih_b, bhh_b, wb, bias, h0mx);
    hipLaunchKernelGGL(k_wq, dim3(512), dim3(256), 0, stream, whh_f, whh_b, wq, wsc);
    hipLaunchKernelGGL(k_h0max, dim3(128), dim3(256), 0, stream, h0, h0mx);
    hipLaunchKernelGGL(k_h0q, dim3(32), dim3(1024), 0, stream, h0, h0mx, h0q);
    hipLaunchKernelGGL(k_gather, dim3(8192), dim3(256), 0, stream, sent, emb, xb);
    hipLaunchKernelGGL(k_pregemm, dim3(512, 32), dim3(256), 0, stream, xb, wb, bias, pre);
    hipLaunchKernelGGL(k_lstm_i8, dim3(8), dim3(1024), 0, stream,
                       wq, wsc, pre, h0q, h0mx, c0, hout);
    hipLaunchKernelGGL(k_feats, dim3(8192), dim3(256), 0, stream, hout, w_out, b_out, feats);
    hipLaunchKernelGGL(k_viterbi, dim3(64), dim3(64), 0, stream, feats, trans, out);
}

// Round 7
// 1615.408 us; speedup vs baseline: 8.2121x; 1.0974x over previous
//
#include <hip/hip_runtime.h>
#include <hip/hip_bf16.h>

// Dims
#define E_ 256
#define H_ 256
#define B_ 64
#define S_ 512
#define T_ 12
#define START_ 10
#define STOP_ 11
#define NEG_ -10000.0f

typedef __attribute__((ext_vector_type(8))) short bf16x8;
typedef __attribute__((ext_vector_type(4))) float f32x4;
typedef __attribute__((ext_vector_type(4))) int i32x4;

__device__ inline unsigned short f2us(float f) {
    __hip_bfloat16 h = __float2bfloat16(f);
    unsigned short u; __builtin_memcpy(&u, &h, 2); return u;
}
__device__ inline float us2f(unsigned short u) {
    unsigned int x = ((unsigned int)u) << 16;
    float f; __builtin_memcpy(&f, &x, 4); return f;
}
__device__ inline float sigm_(float x) {
    return __builtin_amdgcn_rcpf(1.f + __builtin_amdgcn_exp2f(-1.44269504f * x));
}
__device__ inline float tanh_(float x) {
    return 2.f * __builtin_amdgcn_rcpf(1.f + __builtin_amdgcn_exp2f(-2.88539008f * x)) - 1.f;
}

// ---------------- prep: cast Wih to bf16, fold biases, zero h0max slot ----------------
__global__ void k_prep(const float* wih_f, const float* bih_f, const float* bhh_f,
                       const float* wih_b, const float* bih_b, const float* bhh_b,
                       __hip_bfloat16* wb, float* bias, int* h0maxi)
{
    int i = blockIdx.x * 256 + threadIdx.x;   // 0 .. 524287
    int n = i >> 8, k = i & 255;
    float wi = (n < 1024) ? wih_f[n * 256 + k] : wih_b[(n - 1024) * 256 + k];
    wb[i] = __float2bfloat16(wi);
    if (i < 2048)
        bias[i] = (i < 1024) ? (bih_f[i] + bhh_f[i]) : (bih_b[i - 1024] + bhh_b[i - 1024]);
    if (i == 0) *h0maxi = 0;
}

// ---------------- quantize Whh rows to i8 with per-row scale ----------------
__global__ void k_wq(const float* whh_f, const float* whh_b,
                     signed char* wq, float* wscale)
{
    int wv = threadIdx.x >> 6, l = threadIdx.x & 63;
    int n = blockIdx.x * 4 + wv;             // 0..2047
    const float* src = (n < 1024) ? (whh_f + (size_t)n * 256)
                                  : (whh_b + (size_t)(n - 1024) * 256);
    float4 v = *reinterpret_cast<const float4*>(src + l * 4);
    float amax = fmaxf(fmaxf(fabsf(v.x), fabsf(v.y)), fmaxf(fabsf(v.z), fabsf(v.w)));
#pragma unroll
    for (int off = 32; off >= 1; off >>= 1) amax = fmaxf(amax, __shfl_xor(amax, off, 64));
    amax = fmaxf(amax, 1e-20f);
    float inv = 127.f / amax;
    int q0 = (int)rintf(v.x * inv), q1 = (int)rintf(v.y * inv);
    int q2 = (int)rintf(v.z * inv), q3 = (int)rintf(v.w * inv);
    unsigned int pk = (q0 & 255) | ((q1 & 255) << 8) | ((q2 & 255) << 16) | ((q3 & 255) << 24);
    *reinterpret_cast<unsigned int*>(wq + (size_t)n * 256 + l * 4) = pk;
    if (l == 0) wscale[n] = amax * (1.f / 127.f);
}

// ---------------- h0 abs-max (positive-float int atomicMax) ----------------
__global__ void k_h0max(const float* h0, int* h0maxi)
{
    int i = blockIdx.x * 256 + threadIdx.x;   // 32768
    float v = fabsf(h0[i]);
#pragma unroll
    for (int off = 32; off >= 1; off >>= 1) v = fmaxf(v, __shfl_xor(v, off, 64));
    if ((threadIdx.x & 63) == 0) atomicMax(h0maxi, __float_as_int(v));
}

// ---------------- quantize h0 with the global scale ----------------
__global__ void k_h0q(const float* h0, const int* h0maxi, signed char* h0q)
{
    int i = blockIdx.x * 1024 + threadIdx.x;  // 32768
    float s0 = fmaxf(__int_as_float(*h0maxi), 1e-20f);
    h0q[i] = (signed char)(int)rintf(h0[i] * (127.f / s0));
}

// ---------------- gather: xb[s*64+b][e] = bf16(emb[sent[b][s]][e]) ----------------
__global__ void k_gather(const int* sent, const float* emb, __hip_bfloat16* xb)
{
    int gid = blockIdx.x * 256 + threadIdx.x;   // 32768 rows * 64 lanes
    int row = gid >> 6;
    int l = gid & 63;
    int s = row >> 6, b = row & 63;
    int tok = sent[b * S_ + s];
    const float4 v = *reinterpret_cast<const float4*>(emb + (size_t)tok * E_ + l * 4);
    ushort4 pk;
    pk.x = f2us(v.x); pk.y = f2us(v.y); pk.z = f2us(v.z); pk.w = f2us(v.w);
    *reinterpret_cast<ushort4*>(xb + (size_t)row * E_ + l * 4) = pk;
}

// ---------------- pre-GEMM -> FRAGMENT-LAYOUT pre2 ----------------
// pre2 ushort idx = dir*2^25 + (((s*4+bs)*16 + w_l)*64 + lane_l)*16 + g*4 + q_l
// where lane_l = lh_l*16 + lr_l matches the lstm lane that will consume it.
__global__ void k_pregemm(const __hip_bfloat16* xb, const __hip_bfloat16* wb,
                          const float* bias, unsigned short* pre2)
{
    int m0 = blockIdx.x * 64;
    int n0 = blockIdx.y * 64;
    int w = threadIdx.x >> 6, l = threadIdx.x & 63;
    int lr = l & 15, lk = (l >> 4) * 8;
    const __hip_bfloat16* ap = xb + (size_t)(m0 + w * 16 + lr) * 256 + lk;
    const __hip_bfloat16* bpp = wb + (size_t)(n0 + lr) * 256 + lk;
    f32x4 acc[4] = {};
#pragma unroll
    for (int kc = 0; kc < 8; ++kc) {
        bf16x8 a = *reinterpret_cast<const bf16x8*>(ap + kc * 32);
#pragma unroll
        for (int f = 0; f < 4; ++f) {
            bf16x8 bb = *reinterpret_cast<const bf16x8*>(bpp + f * 16 * 256 + kc * 32);
            acc[f] = __builtin_amdgcn_mfma_f32_16x16x32_bf16(a, bb, acc[f], 0, 0, 0);
        }
    }
#pragma unroll
    for (int f = 0; f < 4; ++f) {
        int n = n0 + f * 16 + lr;
        float bsv = bias[n];
        int dirn = n >> 10, j = n & 1023;
        int g = j >> 8, jc = j & 255;
        int wl = jc >> 4, lrl = jc & 15;
#pragma unroll
        for (int q = 0; q < 4; ++q) {
            int m = m0 + w * 16 + (l >> 4) * 4 + q;
            int s = m >> 6, b = m & 63;
            int bsl = b >> 4, lhl = (b >> 2) & 3, ql = b & 3;
            size_t idx = (size_t)dirn * 33554432
                       + ((((size_t)s * 4 + bsl) * 16 + wl) * 64 + lhl * 16 + lrl) * 16
                       + g * 4 + ql;
            pre2[idx] = f2us(acc[f][q] + bsv);
        }
    }
}

// ---------------- recurrent LSTM: i8 MFMA, register-resident Whh, vector pre/h IO ----------
// 8 WGs = (dir x 4 batch-slices of 16), 1024 threads = 16 waves (4/SIMD, 128-reg cap).
// pre2/hout2 in fragment layout: 2 dwordx4 loads + 1 dwordx2 store per lane per step.
__launch_bounds__(1024, 4)
__global__ void k_lstm_i8(const signed char* wq, const float* wsc,
                          const unsigned short* pre2, const signed char* h0q,
                          const int* h0maxi, const float* c0,
                          unsigned short* hout2)
{
    __shared__ signed char hq[2][16][272];   // stride 272B: 16B-aligned, bank-spread
    int bid = blockIdx.x;
    int dir = bid >> 2, bs = bid & 3, b0 = bs * 16;
    int tid = threadIdx.x;
    int w = tid >> 6, l = tid & 63;
    int lr = l & 15, lh = l >> 4;
    int jsub = w * 16;                        // this wave's 16 h-cols

    const signed char* wqp = wq + (size_t)dir * 262144;
    const float* wscp = wsc + dir * 1024;
    // lane's pre slice: 16 contiguous ushorts per step
    const unsigned short* pp = pre2 + (size_t)dir * 33554432
                             + (((size_t)bs * 16 + w) * 64 + l) * 16;
    // lane's h output: 4 contiguous ushorts per step
    unsigned short* hp = hout2 + (size_t)dir * 16777216
                       + (((size_t)bs * 16 + w) * 64 + l) * 4;

    // ---- preload Whh i8 fragments (64 regs) + per-row scales ----
    i32x4 wreg[4][4];
    float sn[4];
#pragma unroll
    for (int f = 0; f < 4; ++f) {
        const signed char* base = wqp + (size_t)(f * 256 + jsub + lr) * 256 + lh * 16;
#pragma unroll
        for (int kc = 0; kc < 4; ++kc)
            wreg[f][kc] = *reinterpret_cast<const i32x4*>(base + kc * 64);
        sn[f] = wscp[f * 256 + jsub + lr];
    }

    // ---- c state: lane owns rows lh*4+q, col jsub+lr ----
    float c[4];
#pragma unroll
    for (int q = 0; q < 4; ++q)
        c[q] = c0[(size_t)(dir * 64 + b0 + lh * 4 + q) * 256 + jsub + lr];

    // ---- init hq[0] from quantized h0 ----
    {
        int idx = tid * 4;
        int row = idx >> 8, k = idx & 255;
        *reinterpret_cast<int*>(&hq[0][row][k]) =
            *reinterpret_cast<const int*>(h0q + (size_t)(dir * 64 + b0 + row) * 256 + k);
    }
    __syncthreads();

    float shs = fmaxf(__int_as_float(*h0maxi), 1e-20f) * (1.f / 127.f);  // t=0 h scale

    for (int t = 0; t < 512; ++t) {
        int s = dir ? (511 - t) : t;
        int cur = t & 1, nxt = cur ^ 1;

        // vector-load pre fragment (32B) early; consumed after MFMA
        const unsigned short* pl = pp + (size_t)s * 65536;
        i32x4 p0 = *reinterpret_cast<const i32x4*>(pl);
        i32x4 p1 = *reinterpret_cast<const i32x4*>(pl + 8);

        // ---- MFMA over K=256 in 4 chunks of 64 ----
        i32x4 acc[4] = {};
#pragma unroll
        for (int kc = 0; kc < 4; ++kc) {
            i32x4 a = *reinterpret_cast<const i32x4*>(&hq[cur][lr][kc * 64 + lh * 16]);
#pragma unroll
            for (int f = 0; f < 4; ++f)
                acc[f] = __builtin_amdgcn_mfma_i32_16x16x64_i8(a, wreg[f][kc], acc[f], 0, 0, 0);
        }

        // ---- gates (i,f,g,o): g = acc*sf + pre (pre unpacked from packed dwords) ----
        float sf0 = shs * sn[0], sf1 = shs * sn[1], sf2 = shs * sn[2], sf3 = shs * sn[3];
        unsigned int u[8];
        u[0] = (unsigned int)p0[0]; u[1] = (unsigned int)p0[1];
        u[2] = (unsigned int)p0[2]; u[3] = (unsigned int)p0[3];
        u[4] = (unsigned int)p1[0]; u[5] = (unsigned int)p1[1];
        u[6] = (unsigned int)p1[2]; u[7] = (unsigned int)p1[3];
        unsigned short hb16[4];
#pragma unroll
        for (int q = 0; q < 4; ++q) {
            // slot g*4+q -> dword g*2+(q>>1), half q&1; bf16<<16 == f32 bits
            float pv0 = (q & 1) ? __uint_as_float(u[0 + (q >> 1)] & 0xffff0000u)
                                : __uint_as_float(u[0 + (q >> 1)] << 16);
            float pv1 = (q & 1) ? __uint_as_float(u[2 + (q >> 1)] & 0xffff0000u)
                                : __uint_as_float(u[2 + (q >> 1)] << 16);
            float pv2 = (q & 1) ? __uint_as_float(u[4 + (q >> 1)] & 0xffff0000u)
                                : __uint_as_float(u[4 + (q >> 1)] << 16);
            float pv3 = (q & 1) ? __uint_as_float(u[6 + (q >> 1)] & 0xffff0000u)
                                : __uint_as_float(u[6 + (q >> 1)] << 16);
            float iv = fmaf((float)acc[0][q], sf0, pv0);
            float fv = fmaf((float)acc[1][q], sf1, pv1);
            float gv = fmaf((float)acc[2][q], sf2, pv2);
            float ov = fmaf((float)acc[3][q], sf3, pv3);
            float cn = sigm_(fv) * c[q] + sigm_(iv) * tanh_(gv);
            c[q] = cn;
            float hv = sigm_(ov) * tanh_(cn);
            hq[nxt][lh * 4 + q][jsub + lr] = (signed char)(int)rintf(hv * 127.f);
            hb16[q] = f2us(hv);
        }
        unsigned int lo = hb16[0] | ((unsigned int)hb16[1] << 16);
        unsigned int hi = hb16[2] | ((unsigned int)hb16[3] << 16);
        *reinterpret_cast<uint2*>(hp + (size_t)s * 16384) = make_uint2(lo, hi);
        shs = 1.f / 127.f;
        __syncthreads();
    }
}

// ---------------- feats: reads fragment-layout hout2 ----------------
__global__ void k_feats(const unsigned short* hout2, const float* w_out, const float* b_out,
                        float* feats)
{
    __shared__ float wsm[12 * 512];
    __shared__ float bsm[12];
    int tid = threadIdx.x;
    for (int i = tid; i < 12 * 512; i += 256) wsm[i] = w_out[i];
    if (tid < 12) bsm[tid] = b_out[tid];
    __syncthreads();
    int w = tid >> 6, l = tid & 63;
    int row = blockIdx.x * 4 + w;
    int s = row >> 6, b = row & 63;
    int bsx = b >> 4, lhb = (b >> 2) & 3, qb = b & 3;
    int wc = l >> 2, lr0 = (l & 3) * 4;       // cols c = 4l..4l+3 = wc*16 + lr0..lr0+3
    size_t base = ((((size_t)s * 4 + bsx) * 16 + wc) * 64 + lhb * 16 + lr0) * 4 + qb;
    float hf[4], hb[4];
#pragma unroll
    for (int i = 0; i < 4; ++i) {
        hf[i] = us2f(hout2[base + (size_t)i * 4]);
        hb[i] = us2f(hout2[16777216 + base + (size_t)i * 4]);
    }
    float outv[12];
#pragma unroll
    for (int tg = 0; tg < 12; ++tg) {
        const float* wr = &wsm[tg * 512];
        float v = 0.f;
#pragma unroll
        for (int i = 0; i < 4; ++i)
            v += wr[l * 4 + i] * hf[i] + wr[256 + l * 4 + i] * hb[i];
#pragma unroll
        for (int off = 32; off >= 1; off >>= 1) v += __shfl_xor(v, off, 64);
        outv[tg] = v;
    }
    if (l == 0) {
#pragma unroll
        for (int tg = 0; tg < 12; ++tg)
            feats[(size_t)row * 12 + tg] = outv[tg] + bsm[tg];
    }
}

// ---------------- Viterbi DP + backtrace ----------------
__global__ void k_viterbi(const float* feats, const float* trans, float* out)
{
    __shared__ unsigned char bp[512][12];
    __shared__ float red[12];
    int b = blockIdx.x, l = threadIdx.x;
    bool act = l < 12;
    float trow[12];
#pragma unroll
    for (int p = 0; p < 12; ++p) trow[p] = act ? trans[l * 12 + p] : 0.f;
    float fv = (l == START_) ? 0.f : NEG_;
    for (int t = 0; t < 512; ++t) {
        float best = -3.0e38f; int bi = 0;
#pragma unroll
        for (int p = 0; p < 12; ++p) {
            float fp = __shfl(fv, p, 64) + trow[p];
            if (fp > best) { best = fp; bi = p; }   // strict > keeps FIRST max (np semantics)
        }
        float ft = act ? feats[(size_t)(t * 64 + b) * 12 + l] : 0.f;
        fv = best + ft;
        if (act) bp[t][l] = (unsigned char)bi;
    }
    float term = fv + (act ? trans[STOP_ * 12 + l] : 0.f);
    if (act) red[l] = term;
    __syncthreads();
    if (l == 0) {
        float bv = red[0]; int bestj = 0;
#pragma unroll
        for (int j = 1; j < 12; ++j)
            if (red[j] > bv) { bv = red[j]; bestj = j; }
        out[b] = bv;
        int curtag = bestj;
        for (int t = 511; t >= 0; --t) {
            out[64 + (size_t)b * 512 + t] = (float)curtag;
            curtag = bp[t][curtag];
        }
    }
}

extern "C" void kernel_launch(void* const* d_in, const int* in_sizes, int n_in,
                              void* d_out, int out_size, void* d_ws, size_t ws_size,
                              hipStream_t stream)
{
    const int*   sent  = (const int*)  d_in[0];
    const float* emb   = (const float*)d_in[1];
    const float* wih_f = (const float*)d_in[2];
    const float* whh_f = (const float*)d_in[3];
    const float* bih_f = (const float*)d_in[4];
    const float* bhh_f = (const float*)d_in[5];
    const float* wih_b = (const float*)d_in[6];
    const float* whh_b = (const float*)d_in[7];
    const float* bih_b = (const float*)d_in[8];
    const float* bhh_b = (const float*)d_in[9];
    const float* w_out = (const float*)d_in[10];
    const float* b_out = (const float*)d_in[11];
    const float* trans = (const float*)d_in[12];
    const float* h0    = (const float*)d_in[13];
    const float* c0    = (const float*)d_in[14];
    float* out = (float*)d_out;

    char* ws = (char*)d_ws;
    __hip_bfloat16* xb    = (__hip_bfloat16*)(ws);               //  16,777,216 B
    __hip_bfloat16* wb    = (__hip_bfloat16*)(ws + 16777216);    //   1,048,576 B
    signed char*    wq    = (signed char*)   (ws + 17825792);    //     524,288 B
    float*          wsc   = (float*)         (ws + 18350080);    //       8,192 B
    signed char*    h0q   = (signed char*)   (ws + 18358272);    //      32,768 B
    int*            h0mx  = (int*)           (ws + 18391040);    //         128 B
    float*          bias  = (float*)         (ws + 18391168);    //       8,192 B
    unsigned short* pre2  = (unsigned short*)(ws + 18399360);    // 134,217,728 B
    unsigned short* hout2 = (unsigned short*)(ws + 152617088);   //  33,554,432 B
    float*          feats = (float*)         (ws + 186171520);   //   1,572,864 B
    // total 187,744,384 B

    hipLaunchKernelGGL(k_prep, dim3(2048), dim3(256), 0, stream,
                       wih_f, bih_f, bhh_f, wih_b, bih_b, bhh_b, wb, bias, h0mx);
    hipLaunchKernelGGL(k_wq, dim3(512), dim3(256), 0, stream, whh_f, whh_b, wq, wsc);
    hipLaunchKernelGGL(k_h0max, dim3(128), dim3(256), 0, stream, h0, h0mx);
    hipLaunchKernelGGL(k_h0q, dim3(32), dim3(1024), 0, stream, h0, h0mx, h0q);
    hipLaunchKernelGGL(k_gather, dim3(8192), dim3(256), 0, stream, sent, emb, xb);
    hipLaunchKernelGGL(k_pregemm, dim3(512, 32), dim3(256), 0, stream, xb, wb, bias, pre2);
    hipLaunchKernelGGL(k_lstm_i8, dim3(8), dim3(1024), 0, stream,
                       wq, wsc, pre2, h0q, h0mx, c0, hout2);
    hipLaunchKernelGGL(k_feats, dim3(8192), dim3(256), 0, stream, hout2, w_out, b_out, feats);
    hipLaunchKernelGGL(k_viterbi, dim3(64), dim3(64), 0, stream, feats, trans, out);
}